// Round 1
// baseline (366.412 us; speedup 1.0000x reference)
//
#include <hip/hip_runtime.h>

// AdderNet 2D: out[n,f,ho,wo] = -sum_{c,kh,kw} |W[f,c,kh,kw] - x_pad[n,c,ho+kh-1,wo+kw-1]|
// x: (16,128,28,28) f32, W: (256,128,3,3) f32, out: (16,256,28,28) f32
// Pure VALU kernel (no MFMA for L1 distance). lane -> output position,
// block -> 16 filters. x taps in VGPRs reused across filters; W via
// wave-uniform s_load (SGPR operands, zero LDS traffic).

#define HW 784        // 28*28
#define WD 28
#define CIN 128
#define OUT_F 256
#define TN 16         // filters per block
#define KD 1152       // 128*9

__global__ __launch_bounds__(256) void adder2d_kernel(
    const float* __restrict__ x,
    const float* __restrict__ Wf,
    float* __restrict__ out)
{
    const int p  = blockIdx.x * 256 + threadIdx.x;   // 0..12543, exact
    const int f0 = blockIdx.y * TN;

    const int n  = p / HW;
    const int r  = p - n * HW;
    const int ho = r / WD;
    const int wo = r - ho * WD;

    // Per-tap validity + clamped (always in-bounds) offsets at c=0.
    bool valid[9];
    int  off[9];
    const int nbase = n * (CIN * HW);
    #pragma unroll
    for (int kh = 0; kh < 3; ++kh) {
        #pragma unroll
        for (int kw = 0; kw < 3; ++kw) {
            const int s = kh * 3 + kw;
            const int h = ho + kh - 1;
            const int w = wo + kw - 1;
            valid[s] = (h >= 0) && (h < WD) && (w >= 0) && (w < WD);
            const int hc = min(max(h, 0), WD - 1);
            const int wc = min(max(w, 0), WD - 1);
            off[s] = nbase + hc * WD + wc;
        }
    }

    float acc[TN];
    #pragma unroll
    for (int i = 0; i < TN; ++i) acc[i] = 0.0f;

    for (int c = 0; c < CIN; ++c) {
        // 9 taps for this channel into registers (masked for padding).
        float xv[9];
        #pragma unroll
        for (int s = 0; s < 9; ++s) {
            const float v = x[off[s]];
            xv[s] = valid[s] ? v : 0.0f;
            off[s] += HW;            // advance one channel
        }
        // 16 filters x 9 taps, W reads are wave-uniform -> s_load.
        #pragma unroll
        for (int ff = 0; ff < TN; ++ff) {
            const float* wrow = Wf + (size_t)(f0 + ff) * KD + c * 9;
            #pragma unroll
            for (int s = 0; s < 9; ++s) {
                acc[ff] += fabsf(wrow[s] - xv[s]);
            }
        }
    }

    // out[n][f][ho][wo], negated (AdderNet = -cdist)
    const int obase = n * (OUT_F * HW) + ho * WD + wo;
    #pragma unroll
    for (int ff = 0; ff < TN; ++ff) {
        out[obase + (f0 + ff) * HW] = -acc[ff];
    }
}

extern "C" void kernel_launch(void* const* d_in, const int* in_sizes, int n_in,
                              void* d_out, int out_size, void* d_ws, size_t ws_size,
                              hipStream_t stream) {
    const float* x  = (const float*)d_in[0];
    const float* Wf = (const float*)d_in[1];
    float* out = (float*)d_out;

    dim3 grid(12544 / 256, OUT_F / TN);   // (49, 16)
    dim3 block(256);
    adder2d_kernel<<<grid, block, 0, stream>>>(x, Wf, out);
}

// Round 2
// 293.442 us; speedup vs baseline: 1.2487x; 1.2487x over previous
//
#include <hip/hip_runtime.h>

// AdderNet 2D: out[n,f,ho,wo] = -sum_{c,kh,kw} |W[f,c,kh,kw] - x_pad[n,c,ho+kh-1,wo+kw-1]|
// x: (16,128,28,28) f32, W: (256,128,3,3) f32, out: (16,256,28,28) f32
//
// R2: W staged in LDS per block, transposed to [c][ff][s] so each channel's
// 8x9 filter slice is 288 contiguous bytes -> wave-uniform broadcast
// ds_read_b128 (conflict-free), removing the scattered s_load / scalar-K$
// bottleneck seen in R1 (VALUBusy 55%, SMEM-stalled). TN=8 -> 36 KB LDS ->
// 4 blocks/CU = 16 waves/CU for latency hiding.

#define HW 784        // 28*28
#define WD 28
#define CIN 128
#define OUT_F 256
#define TN 8          // filters per block
#define KD 1152       // 128*9

__global__ __launch_bounds__(256) void adder2d_kernel(
    const float* __restrict__ x,
    const float* __restrict__ Wf,
    float* __restrict__ out)
{
    __shared__ float Wl[CIN * TN * 9];   // [c][ff][s], 36864 B

    const int tid = threadIdx.x;
    const int p   = blockIdx.x * 256 + tid;   // 0..12543, exact
    const int f0  = blockIdx.y * TN;

    // ---- stage W slice (TN*1152 dwords) coalesced, transposed to [c][ff][s]
    {
        const float* wsrc = Wf + (size_t)f0 * KD;
        #pragma unroll
        for (int k = 0; k < (TN * KD) / 256; ++k) {
            const int gidx = tid + k * 256;        // linear over [ff][c][s]
            const float v = wsrc[gidx];
            const int ff  = gidx / KD;
            const int rem = gidx - ff * KD;        // c*9 + s
            Wl[rem * TN + ff] = v;                 // [c][s][ff]? no: see below
        }
    }
    // NOTE on layout: rem = c*9+s, so address rem*TN+ff = (c*9+s)*TN+ff
    //  -> [c][s][ff] layout, 288 B contiguous per channel. Reads below match.

    __syncthreads();

    const int n  = p / HW;
    const int r  = p - n * HW;
    const int ho = r / WD;
    const int wo = r - ho * WD;

    // Per-tap validity + clamped (always in-bounds) offsets at c=0.
    bool valid[9];
    int  off[9];
    const int nbase = n * (CIN * HW);
    #pragma unroll
    for (int kh = 0; kh < 3; ++kh) {
        #pragma unroll
        for (int kw = 0; kw < 3; ++kw) {
            const int s = kh * 3 + kw;
            const int h = ho + kh - 1;
            const int w = wo + kw - 1;
            valid[s] = (h >= 0) && (h < WD) && (w >= 0) && (w < WD);
            const int hc = min(max(h, 0), WD - 1);
            const int wc = min(max(w, 0), WD - 1);
            off[s] = nbase + hc * WD + wc;
        }
    }

    float acc[TN];
    #pragma unroll
    for (int i = 0; i < TN; ++i) acc[i] = 0.0f;

    for (int c = 0; c < CIN; ++c) {
        // 9 taps for this channel into registers (masked for padding).
        float xv[9];
        #pragma unroll
        for (int s = 0; s < 9; ++s) {
            const float v = x[off[s]];
            xv[s] = valid[s] ? v : 0.0f;
            off[s] += HW;            // advance one channel
        }
        // TN filters x 9 taps; W from LDS, wave-uniform broadcast reads.
        const float* wch = &Wl[c * (9 * TN)];   // [s][ff] within channel
        #pragma unroll
        for (int s = 0; s < 9; ++s) {
            #pragma unroll
            for (int ff = 0; ff < TN; ++ff) {
                acc[ff] += fabsf(wch[s * TN + ff] - xv[s]);
            }
        }
    }

    // out[n][f][ho][wo], negated (AdderNet = -cdist)
    const int obase = n * (OUT_F * HW) + ho * WD + wo;
    #pragma unroll
    for (int ff = 0; ff < TN; ++ff) {
        out[obase + (f0 + ff) * HW] = -acc[ff];
    }
}

extern "C" void kernel_launch(void* const* d_in, const int* in_sizes, int n_in,
                              void* d_out, int out_size, void* d_ws, size_t ws_size,
                              hipStream_t stream) {
    const float* x  = (const float*)d_in[0];
    const float* Wf = (const float*)d_in[1];
    float* out = (float*)d_out;

    dim3 grid(12544 / 256, OUT_F / TN);   // (49, 32)
    dim3 block(256);
    adder2d_kernel<<<grid, block, 0, stream>>>(x, Wf, out);
}

// Round 5
// 272.318 us; speedup vs baseline: 1.3455x; 1.0776x over previous
//
#include <hip/hip_runtime.h>

// AdderNet 2D: out[n,f,ho,wo] = -sum_{c,kh,kw} |W[f,c,kh,kw] - x_pad[n,c,ho+kh-1,wo+kw-1]|
// x: (16,128,28,28) f32, W: (256,128,3,3) f32, out: (16,256,28,28) f32
//
// R5 = R4 with the cvt_pkrtz return-type compile fix (bit_cast to half2v).
// Packed-f16 math, zero workspace, all conversion in-kernel:
//  - W: staged to LDS as half2 (channel pairs) via v_cvt_pkrtz during the
//    one-time block staging; LDS writes linear (conflict-free), inner reads
//    wave-uniform broadcast ds_read_b128.
//  - x: 2 f32 loads per tap (2nd folds to imm offset:3136) + cvt_pkrtz +
//    one cndmask for zero-padding (R2's proven clamp+valid scheme).
// Inner loop per 2 elements: v_pk_add_f16 (sub) + v_and_b32 (packed abs)
// + v_dot2_f32_f16 (packed sum, fp32 acc) = 1.5 VALU/elem.

typedef __attribute__((ext_vector_type(2))) _Float16 half2v;

#define HW 784
#define WD 28
#define CIN 128
#define C2 64            // channel pairs
#define OUT_F 256
#define TN 8             // filters per block
#define WL_N (C2 * 9 * TN)   // 4608 half2 = 18432 B

static __device__ __forceinline__ half2v cvt2(float a, float b) {
    return __builtin_bit_cast(half2v, __builtin_amdgcn_cvt_pkrtz(a, b));
}

__global__ __launch_bounds__(256, 6) void adder2d_kernel(
    const float* __restrict__ x,
    const float* __restrict__ Wf,
    float* __restrict__ out)
{
    __shared__ half2v Wl[WL_N];   // [c2][s][ff]

    const int tid = threadIdx.x;
    const int f0  = blockIdx.y * TN;

    // ---- stage W with f32->f16 pair conversion.
    // m = c2*72 + s*8 + ff  == the exact read index -> linear LDS writes.
    #pragma unroll
    for (int k = 0; k < WL_N / 256; ++k) {     // 18 iters
        const int m  = tid + k * 256;
        const int ff = m & 7;
        const int q  = m >> 3;                 // c2*9 + s
        const int s  = q % 9;
        const int c2 = q / 9;
        const float* b = Wf + ((size_t)(f0 + ff) * CIN + 2 * c2) * 9 + s;
        Wl[m] = cvt2(b[0], b[9]);              // (ch 2c2, ch 2c2+1)
    }
    __syncthreads();

    const int p  = blockIdx.x * 256 + tid;   // 0..12543, exact
    const int n  = p / HW;
    const int r  = p - n * HW;
    const int ho = r / WD;
    const int wo = r - ho * WD;

    // Per-tap validity + clamped (always in-bounds) offsets at channel 0.
    bool valid[9];
    int  off[9];
    const int nbase = n * (CIN * HW);
    #pragma unroll
    for (int kh = 0; kh < 3; ++kh) {
        #pragma unroll
        for (int kw = 0; kw < 3; ++kw) {
            const int s = kh * 3 + kw;
            const int h = ho + kh - 1;
            const int w = wo + kw - 1;
            valid[s] = (h >= 0) && (h < WD) && (w >= 0) && (w < WD);
            const int hc = min(max(h, 0), WD - 1);
            const int wc = min(max(w, 0), WD - 1);
            off[s] = nbase + hc * WD + wc;
        }
    }

    float acc[TN];
    #pragma unroll
    for (int i = 0; i < TN; ++i) acc[i] = 0.0f;

    half2v zero2; zero2[0] = (_Float16)0.f; zero2[1] = (_Float16)0.f;
    half2v one2;  one2[0]  = (_Float16)1.f; one2[1]  = (_Float16)1.f;

    #pragma unroll 1
    for (int c2 = 0; c2 < C2; ++c2) {
        // 9 taps, each a channel-pair: two f32 loads + packed convert + pad mask
        half2v xv[9];
        #pragma unroll
        for (int s = 0; s < 9; ++s) {
            const float v0 = x[off[s]];
            const float v1 = x[off[s] + HW];          // imm offset:3136
            const half2v t = cvt2(v0, v1);
            xv[s] = valid[s] ? t : zero2;             // zero-pad contributes |w|
            off[s] += 2 * HW;                         // next channel pair
        }
        const half2v* wc = &Wl[c2 * (9 * TN)];
        #pragma unroll
        for (int s = 0; s < 9; ++s) {
            const half2v xs = xv[s];
            #pragma unroll
            for (int ff = 0; ff < TN; ++ff) {
                half2v d = wc[s * TN + ff] - xs;                              // v_pk_add_f16 (neg)
                unsigned du = __builtin_bit_cast(unsigned, d) & 0x7FFF7FFFu;  // packed abs
                half2v a = __builtin_bit_cast(half2v, du);
#if __has_builtin(__builtin_amdgcn_fdot2)
                acc[ff] = __builtin_amdgcn_fdot2(a, one2, acc[ff], false);    // v_dot2_f32_f16
#else
                acc[ff] += (float)a[0] + (float)a[1];
#endif
            }
        }
    }

    const int obase = n * (OUT_F * HW) + ho * WD + wo;
    #pragma unroll
    for (int ff = 0; ff < TN; ++ff) {
        out[obase + (f0 + ff) * HW] = -acc[ff];
    }
}

extern "C" void kernel_launch(void* const* d_in, const int* in_sizes, int n_in,
                              void* d_out, int out_size, void* d_ws, size_t ws_size,
                              hipStream_t stream) {
    const float* x  = (const float*)d_in[0];
    const float* Wf = (const float*)d_in[1];
    float* out = (float*)d_out;

    dim3 grid(12544 / 256, OUT_F / TN);   // (49, 32)
    adder2d_kernel<<<grid, dim3(256), 0, stream>>>(x, Wf, out);
}